// Round 16
// baseline (170.765 us; speedup 1.0000x reference)
//
#include <hip/hip_runtime.h>
#include <hip/hip_bf16.h>

// ---------------------------------------------------------------------------
// GCN classifier.  R4: bucketed counting-sort CSR.  R6: MFMA GEMM.
// R9: fixed buckets, agg unroll 8.  R10: pre-scale + pool fusion.
// R11/R13: scatter||gemm1; csr_build+poolzero.  R14: gemm2 fused into agg1.
// R12 (REVERTED): XCD slicing (sub-line gathers, undefined XCD mapping).
// R15 (REVERTED): degree-sort perm — balanced compute but scattered Hs2
//      writes (partial-line RMW, FETCH +5MB) + serial perm load on the
//      gather critical path. Net -5us.
// R16: wave-autonomous phase 2 in agg1_gemm2 (NO __syncthreads). Wave w
//      computes its OWN 4 rows x 128 cols (8 ct x 4 k MFMAs); A-frag rows
//      outside its range read unsynced LDS garbage and are DISCARDED (MFMA
//      rows independent; stores masked lg==w). Block no longer waits on its
//      slowest node (max-of-16 -> max-of-4 per wave). W2t (32KB) is read
//      fully per wave but exactly fits L1 and stays hot. Bit-identical.
// ---------------------------------------------------------------------------

typedef unsigned int uint;
typedef unsigned short ushort;
typedef __attribute__((ext_vector_type(8))) short bf16x8;
typedef __attribute__((ext_vector_type(4))) float f32x4;

__device__ inline float bf_lo(uint u) { return __uint_as_float(u << 16); }
__device__ inline float bf_hi(uint u) { return __uint_as_float(u & 0xffff0000u); }
__device__ inline ushort f2bf(float f) {           // round-to-nearest-even
    uint u = __float_as_uint(f);
    return (ushort)((u + 0x7fffu + ((u >> 16) & 1u)) >> 16);
}
__device__ inline uint pack2bf(float a, float b) {
    return (uint)f2bf(a) | ((uint)f2bf(b) << 16);
}

#define EPB 2048   // edges per block in bucketing kernels
#define CAP 8192   // per-bucket staged-edge capacity (avg 4082, Poisson tail ~0)

// ---- 0) zero bcur (block 0) + convert both weights (blocks 1..128) --------
__global__ __launch_bounds__(256) void init0(int* __restrict__ bcur,
                                             const float* __restrict__ W1,
                                             const float* __restrict__ W2,
                                             ushort* __restrict__ W1t,
                                             ushort* __restrict__ W2t) {
    if (blockIdx.x == 0) {
        bcur[threadIdx.x] = 0;
    } else {
        int i = (blockIdx.x - 1) * 256 + threadIdx.x;    // 0..32767
        const float* Ws = (i < 16384) ? W1 : W2;
        ushort* Wd      = (i < 16384) ? W1t : W2t;
        int j = i & 16383;
        int nn = j >> 7, k = j & 127;
        Wd[j] = f2bf(Ws[k * 128 + nn]);
    }
}

// ---- scatter body (uses caller-provided LDS: 1284 ints + 2048 uints) ------
__device__ void scatter_body(int* lds,
                             const int* __restrict__ src,
                             const int* __restrict__ dst,
                             int* __restrict__ bcur,
                             uint* __restrict__ bstage,
                             int E, int NB, int bid) {
    int*  lh    = lds;            // 256
    int*  lbase = lds + 256;      // 257
    int*  gbase = lds + 513;      // 256
    int*  lcur  = lds + 769;      // 256
    int*  ls    = lds + 1025;     // 256
    uint* stage = (uint*)(lds + 1284);   // 2048
    const int t = threadIdx.x;
    const int base = bid * EPB;
    const int end  = min(E, base + EPB);
    const int tot  = end - base;

    lh[t] = 0;
    __syncthreads();

    uint pk[8]; int bk[8]; int cnt = 0;
    for (int i = base + t; i < end; i += 256) {
        int s = src[i];
        uint d = (uint)dst[i];
        bk[cnt] = (int)(d >> 8);
        pk[cnt] = (uint)s | ((d & 255u) << 24);
        atomicAdd(&lh[bk[cnt]], 1);
        ++cnt;
    }
    __syncthreads();

    if (t < NB && lh[t]) gbase[t] = t * CAP + atomicAdd(&bcur[t], lh[t]);
    {
        int v = lh[t];
        ls[t] = v;
        __syncthreads();
        for (int off = 1; off < 256; off <<= 1) {
            int x = (t >= off) ? ls[t - off] : 0;
            __syncthreads();
            ls[t] += x;
            __syncthreads();
        }
        lbase[t] = ls[t] - v;
        if (t == 255) lbase[256] = ls[255];
        lcur[t] = 0;
    }
    __syncthreads();

    for (int j = 0; j < cnt; ++j) {
        int p = lbase[bk[j]] + atomicAdd(&lcur[bk[j]], 1);
        stage[p] = pk[j];
    }
    __syncthreads();

    for (int i = t; i < tot; i += 256) {
        int lo = 0, hi = 256;
        while (lo + 1 < hi) {
            int mid = (lo + hi) >> 1;
            if (lbase[mid] <= i) lo = mid; else hi = mid;
        }
        bstage[gbase[lo] + (i - lbase[lo])] = stage[i];
    }
}

// ---- csr_build body (uses caller-provided 4KB of LDS) ---------------------
__device__ void csr_body(int* lds,
                         const uint* __restrict__ bstage,
                         const int* __restrict__ bcur,
                         float* __restrict__ dis,
                         int* __restrict__ rbeg,
                         int* __restrict__ rend,
                         int* __restrict__ csr,
                         int N, int b) {
    int* lh    = lds;
    int* ls    = lds + 256;
    int* lbase = lds + 512;
    int* lcur  = lds + 768;
    const int t = threadIdx.x;
    const int base  = b * CAP;
    const int cntb  = bcur[b];
    const int n0    = b << 8;
    const int nn    = min(256, N - n0);

    lh[t] = 0;
    __syncthreads();
    for (int i = t; i < cntb; i += 256)
        atomicAdd(&lh[bstage[base + i] >> 24], 1);
    __syncthreads();

    const int v = lh[t];
    ls[t] = v;
    __syncthreads();
    for (int off = 1; off < 256; off <<= 1) {
        int x = (t >= off) ? ls[t - off] : 0;
        __syncthreads();
        ls[t] += x;
        __syncthreads();
    }
    lbase[t] = ls[t] - v;
    lcur[t] = 0;
    if (t < nn) {
        dis[n0 + t]  = rsqrtf((float)v + 1.0f);
        rbeg[n0 + t] = base + lbase[t];
        rend[n0 + t] = base + lbase[t] + v;
    }
    __syncthreads();

    for (int i = t; i < cntb; i += 256) {
        uint e = bstage[base + i];
        int dl = (int)(e >> 24);
        int pos = base + lbase[dl] + atomicAdd(&lcur[dl], 1);
        csr[pos] = (int)(e & 0xFFFFFFu);
    }
}

// ---- MFMA GEMM body (uses caller-provided 32KB LDS) ------------------------
// Out_bf16[n,128] = (A[n,128] @ W[128,128]) * (SCALE ? dis[row] : 1)
template<bool GATHER, bool SCALE>
__device__ void gemm_body(ushort* wl,
                          const ushort* __restrict__ Xbf,
                          const int* __restrict__ tokens,
                          const float* __restrict__ emb,
                          const ushort* __restrict__ Wt,
                          const float* __restrict__ dis,
                          ushort* __restrict__ Out, int n, int bid) {
    const int tid = threadIdx.x;
    {
        const int row  = tid >> 1;
        const int half = tid & 1;
        const int base = row * 256 + half * 128;
#pragma unroll
        for (int i = 0; i < 8; ++i) {
            int off = base + i * 16;
            uint4 v = *(const uint4*)((const char*)Wt + off);
            int swz = off ^ ((row & 7) << 4);
            *(uint4*)((char*)wl + swz) = v;
        }
    }
    __syncthreads();

    const int w  = tid >> 6;
    const int l  = tid & 63;
    const int lr = l & 15;
    const int lg = l >> 4;
    const int rowBase = bid * 128 + w * 32;

    f32x4 acc[2][8];
#pragma unroll
    for (int s = 0; s < 2; ++s)
#pragma unroll
        for (int ct = 0; ct < 8; ++ct) acc[s][ct] = (f32x4){0.f, 0.f, 0.f, 0.f};

    bf16x8 afrag[2][4];
#pragma unroll
    for (int s = 0; s < 2; ++s) {
        const int row = rowBase + s * 16 + lr;
        if (row < n) {
            if (GATHER) {
                const int tok = tokens[row];
                if (tok != 0) {
                    const float* ep = emb + (size_t)tok * 128;
#pragma unroll
                    for (int kk = 0; kk < 4; ++kk) {
                        const float* q = ep + kk * 32 + lg * 8;
                        float4 lo = *(const float4*)q;
                        float4 hi = *(const float4*)(q + 4);
                        uint4 pk;
                        pk.x = pack2bf(lo.x, lo.y); pk.y = pack2bf(lo.z, lo.w);
                        pk.z = pack2bf(hi.x, hi.y); pk.w = pack2bf(hi.z, hi.w);
                        union { uint4 u; bf16x8 b; } c; c.u = pk;
                        afrag[s][kk] = c.b;
                    }
                } else {
#pragma unroll
                    for (int kk = 0; kk < 4; ++kk) afrag[s][kk] = (bf16x8){0,0,0,0,0,0,0,0};
                }
            } else {
                const ushort* xp = Xbf + (size_t)row * 128;
#pragma unroll
                for (int kk = 0; kk < 4; ++kk)
                    afrag[s][kk] = *(const bf16x8*)(xp + kk * 32 + lg * 8);
            }
        } else {
#pragma unroll
            for (int kk = 0; kk < 4; ++kk) afrag[s][kk] = (bf16x8){0,0,0,0,0,0,0,0};
        }
    }

#pragma unroll
    for (int ct = 0; ct < 8; ++ct) {
#pragma unroll
        for (int kk = 0; kk < 4; ++kk) {
            const int nrow = ct * 16 + lr;
            int off = nrow * 256 + kk * 64 + lg * 16;
            off ^= ((nrow & 7) << 4);
            bf16x8 b = *(const bf16x8*)((const char*)wl + off);
            acc[0][ct] = __builtin_amdgcn_mfma_f32_16x16x32_bf16(afrag[0][kk], b, acc[0][ct], 0, 0, 0);
            acc[1][ct] = __builtin_amdgcn_mfma_f32_16x16x32_bf16(afrag[1][kk], b, acc[1][ct], 0, 0, 0);
        }
    }

#pragma unroll
    for (int s = 0; s < 2; ++s) {
#pragma unroll
        for (int r = 0; r < 4; ++r) {
            const int row = rowBase + s * 16 + lg * 4 + r;
            if (row < n) {
                const float sc = SCALE ? dis[row] : 1.0f;
                ushort* op = Out + (size_t)row * 128 + lr;
#pragma unroll
                for (int ct = 0; ct < 8; ++ct)
                    op[ct * 16] = f2bf(acc[s][ct][r] * sc);
            }
        }
    }
}

// ---- L1: fused scatter (blocks 0..EB) | gemm1 (EB..EB+GB) ------------------
__global__ __launch_bounds__(256) void scatter_gemm1_fused(const int* __restrict__ src,
                                                           const int* __restrict__ dst,
                                                           int* __restrict__ bcur,
                                                           uint* __restrict__ bstage,
                                                           const int* __restrict__ tokens,
                                                           const float* __restrict__ emb,
                                                           const ushort* __restrict__ W1t,
                                                           ushort* __restrict__ H,
                                                           int E, int NB, int EB, int N) {
    __shared__ ushort wl[128 * 128];   // 32KB; scatter path aliases 13.3KB
    const int b = blockIdx.x;
    if (b < EB) {
        scatter_body((int*)wl, src, dst, bcur, bstage, E, NB, b);
    } else {
        gemm_body<true, false>(wl, nullptr, tokens, emb, W1t, nullptr, H, N, b - EB);
    }
}

// ---- L2: csr_build (blocks 0..NB) | pooled zero ----------------------------
__global__ __launch_bounds__(256) void csr_poolz(const uint* __restrict__ bstage,
                                                 const int* __restrict__ bcur,
                                                 float* __restrict__ dis,
                                                 int* __restrict__ rbeg,
                                                 int* __restrict__ rend,
                                                 int* __restrict__ csr,
                                                 int4* __restrict__ poolz, int pz4,
                                                 int N, int NB) {
    __shared__ int lds[1024];
    const int b = blockIdx.x;
    if (b < NB) {
        csr_body(lds, bstage, bcur, dis, rbeg, rend, csr, N, b);
    } else {
        int i = (b - NB) * 256 + threadIdx.x;
        if (i < pz4) poolz[i] = make_int4(0, 0, 0, 0);
    }
}

// ---------------------------------------------------------------------------
// L3: agg1 + gemm2 fused, wave-autonomous phase 2 (NO __syncthreads).
// Phase 1 (identical math to R13 agg1): per node (16 lanes, full 256B rows)
//   o = relu( dn*sum_e H[src]*dis[src] + H[node]*dn^2 + b1 )   [f32 -> bf16]
//   staged into 4KB LDS with (row&7)<<4 swizzle.
// Phase 2: wave w computes rows w*4..w*4+3 x 128 cols: 8 ct x 4 k MFMAs.
//   A-frag rows outside the wave's range read unsynced LDS (garbage OK —
//   MFMA rows independent); stores masked to lg==w. W2t read per wave (32KB,
//   L1-resident). Waves retire at their own max-of-4, no block straggler.
// ---------------------------------------------------------------------------
__global__ __launch_bounds__(256) void agg1_gemm2(const ushort* __restrict__ H,
                                                  const float* __restrict__ dis,
                                                  const int* __restrict__ rbeg,
                                                  const int* __restrict__ rend,
                                                  const int* __restrict__ csr,
                                                  const float* __restrict__ bias,
                                                  const ushort* __restrict__ W2t,
                                                  ushort* __restrict__ Hs2,
                                                  int n) {
    const int g = threadIdx.x >> 4;
    const int l = threadIdx.x & 15;
    const int node = blockIdx.x * 16 + g;
    const bool valid = node < n;

    float s0_=0.f,s1_=0.f,s2_=0.f,s3_=0.f,s4_=0.f,s5_=0.f,s6_=0.f,s7_=0.f;
    float dn = 0.f;
    const float4 bA = *(const float4*)&bias[l * 8];
    const float4 bB = *(const float4*)&bias[l * 8 + 4];
    float hx0=0.f,hx1=0.f,hx2=0.f,hx3=0.f,hx4=0.f,hx5=0.f,hx6=0.f,hx7=0.f;

    if (valid) {
        dn = dis[node];
        const uint4 hq = *(const uint4*)(H + (size_t)node * 128 + l * 8);
        hx0 = bf_lo(hq.x); hx1 = bf_hi(hq.x);
        hx2 = bf_lo(hq.y); hx3 = bf_hi(hq.y);
        hx4 = bf_lo(hq.z); hx5 = bf_hi(hq.z);
        hx6 = bf_lo(hq.w); hx7 = bf_hi(hq.w);

        const int e0 = rbeg[node];
        const int e1 = rend[node];
        int e = e0;
        for (; e + 8 <= e1; e += 8) {
            int a[8];
#pragma unroll
            for (int j = 0; j < 8; ++j) a[j] = csr[e + j];
            float w[8];
#pragma unroll
            for (int j = 0; j < 8; ++j) w[j] = dis[a[j]];
            uint4 h[8];
#pragma unroll
            for (int j = 0; j < 8; ++j) h[j] = *(const uint4*)(H + (size_t)a[j] * 128 + l * 8);
#pragma unroll
            for (int j = 0; j < 8; ++j) {
                s0_ += bf_lo(h[j].x) * w[j]; s1_ += bf_hi(h[j].x) * w[j];
                s2_ += bf_lo(h[j].y) * w[j]; s3_ += bf_hi(h[j].y) * w[j];
                s4_ += bf_lo(h[j].z) * w[j]; s5_ += bf_hi(h[j].z) * w[j];
                s6_ += bf_lo(h[j].w) * w[j]; s7_ += bf_hi(h[j].w) * w[j];
            }
        }
        for (; e + 4 <= e1; e += 4) {
            int a[4];
#pragma unroll
            for (int j = 0; j < 4; ++j) a[j] = csr[e + j];
            float w[4];
#pragma unroll
            for (int j = 0; j < 4; ++j) w[j] = dis[a[j]];
            uint4 h[4];
#pragma unroll
            for (int j = 0; j < 4; ++j) h[j] = *(const uint4*)(H + (size_t)a[j] * 128 + l * 8);
#pragma unroll
            for (int j = 0; j < 4; ++j) {
                s0_ += bf_lo(h[j].x) * w[j]; s1_ += bf_hi(h[j].x) * w[j];
                s2_ += bf_lo(h[j].y) * w[j]; s3_ += bf_hi(h[j].y) * w[j];
                s4_ += bf_lo(h[j].z) * w[j]; s5_ += bf_hi(h[j].z) * w[j];
                s6_ += bf_lo(h[j].w) * w[j]; s7_ += bf_hi(h[j].w) * w[j];
            }
        }
        for (; e < e1; ++e) {
            const int a = csr[e];
            const float w = dis[a];
            const uint4 h = *(const uint4*)(H + (size_t)a * 128 + l * 8);
            s0_ += bf_lo(h.x)*w; s1_ += bf_hi(h.x)*w;
            s2_ += bf_lo(h.y)*w; s3_ += bf_hi(h.y)*w;
            s4_ += bf_lo(h.z)*w; s5_ += bf_hi(h.z)*w;
            s6_ += bf_lo(h.w)*w; s7_ += bf_hi(h.w)*w;
        }
    }

    const float self = dn * dn;
    uint4 o;
    o.x = pack2bf(fmaxf(s0_ * dn + hx0 * self + bA.x, 0.0f),
                  fmaxf(s1_ * dn + hx1 * self + bA.y, 0.0f));
    o.y = pack2bf(fmaxf(s2_ * dn + hx2 * self + bA.z, 0.0f),
                  fmaxf(s3_ * dn + hx3 * self + bA.w, 0.0f));
    o.z = pack2bf(fmaxf(s4_ * dn + hx4 * self + bB.x, 0.0f),
                  fmaxf(s5_ * dn + hx5 * self + bB.y, 0.0f));
    o.w = pack2bf(fmaxf(s6_ * dn + hx6 * self + bB.z, 0.0f),
                  fmaxf(s7_ * dn + hx7 * self + bB.w, 0.0f));

    // stage X2 tile (16 rows x 128 cols bf16) in LDS, (row&7)<<4 swizzle.
    // NO barrier: each wave only relies on its OWN 4 rows (RAW within wave
    // ordered by lgkmcnt); other rows may be garbage and are discarded.
    __shared__ ushort x2[16 * 128];
    {
        int boff = (g << 8) + (l << 4);
        boff ^= (g & 7) << 4;
        *(uint4*)((char*)x2 + boff) = o;
    }

    // ---- phase 2 (wave-autonomous): wave w -> rows w*4..w*4+3, all 128 cols
    const int w   = threadIdx.x >> 6;
    const int l64 = threadIdx.x & 63;
    const int lr  = l64 & 15;
    const int lg  = l64 >> 4;

    bf16x8 afr[4];
#pragma unroll
    for (int kk = 0; kk < 4; ++kk) {
        int roff = (lr << 8) + (kk << 6) + (lg << 4);
        roff ^= (lr & 7) << 4;
        afr[kk] = *(const bf16x8*)((const char*)x2 + roff);
    }

    f32x4 acc[8];
#pragma unroll
    for (int ct = 0; ct < 8; ++ct) acc[ct] = (f32x4){0.f, 0.f, 0.f, 0.f};
#pragma unroll
    for (int ct = 0; ct < 8; ++ct) {
#pragma unroll
        for (int kk = 0; kk < 4; ++kk) {
            bf16x8 b = *(const bf16x8*)(W2t + (size_t)(ct * 16 + lr) * 128 + kk * 32 + lg * 8);
            acc[ct] = __builtin_amdgcn_mfma_f32_16x16x32_bf16(afr[kk], b, acc[ct], 0, 0, 0);
        }
    }

    if (lg == w) {
#pragma unroll
        for (int r = 0; r < 4; ++r) {
            const int row = blockIdx.x * 16 + w * 4 + r;
            if (row < n) {
                const float sc = dis[row];
                ushort* op = Hs2 + (size_t)row * 128 + lr;
#pragma unroll
                for (int ct = 0; ct < 8; ++ct)
                    op[ct * 16] = f2bf(acc[ct][r] * sc);
            }
        }
    }
}

// ---------------------------------------------------------------------------
// agg2 over pre-scaled Hs (natural node order), fused with mean-pool partials.
// ---------------------------------------------------------------------------
__global__ __launch_bounds__(256) void aggregate_pool(const ushort* __restrict__ H,
                                                      const float* __restrict__ dis,
                                                      const int* __restrict__ rbeg,
                                                      const int* __restrict__ rend,
                                                      const int* __restrict__ csr,
                                                      const float* __restrict__ bias,
                                                      const int* __restrict__ batch,
                                                      float* __restrict__ pooled,
                                                      int n) {
    const int g = threadIdx.x >> 4;
    const int l = threadIdx.x & 15;
    const int node = blockIdx.x * 16 + g;
    const bool valid = node < n;

    float s0_=0.f,s1_=0.f,s2_=0.f,s3_=0.f,s4_=0.f,s5_=0.f,s6_=0.f,s7_=0.f;
    float dn = 0.f;
    const float4 bA = *(const float4*)&bias[l * 8];
    const float4 bB = *(const float4*)&bias[l * 8 + 4];

    if (valid) {
        dn = dis[node];
        const uint4 hq = *(const uint4*)(H + (size_t)node * 128 + l * 8);
        s0_ = bf_lo(hq.x); s1_ = bf_hi(hq.x);
        s2_ = bf_lo(hq.y); s3_ = bf_hi(hq.y);
        s4_ = bf_lo(hq.z); s5_ = bf_hi(hq.z);
        s6_ = bf_lo(hq.w); s7_ = bf_hi(hq.w);

        const int e0 = rbeg[node];
        const int e1 = rend[node];
        int e = e0;
        for (; e + 8 <= e1; e += 8) {
            int a[8];
#pragma unroll
            for (int j = 0; j < 8; ++j) a[j] = csr[e + j];
            uint4 h[8];
#pragma unroll
            for (int j = 0; j < 8; ++j) h[j] = *(const uint4*)(H + (size_t)a[j] * 128 + l * 8);
#pragma unroll
            for (int j = 0; j < 8; ++j) {
                s0_ += bf_lo(h[j].x); s1_ += bf_hi(h[j].x);
                s2_ += bf_lo(h[j].y); s3_ += bf_hi(h[j].y);
                s4_ += bf_lo(h[j].z); s5_ += bf_hi(h[j].z);
                s6_ += bf_lo(h[j].w); s7_ += bf_hi(h[j].w);
            }
        }
        for (; e + 4 <= e1; e += 4) {
            int a[4];
#pragma unroll
            for (int j = 0; j < 4; ++j) a[j] = csr[e + j];
            uint4 h[4];
#pragma unroll
            for (int j = 0; j < 4; ++j) h[j] = *(const uint4*)(H + (size_t)a[j] * 128 + l * 8);
#pragma unroll
            for (int j = 0; j < 4; ++j) {
                s0_ += bf_lo(h[j].x); s1_ += bf_hi(h[j].x);
                s2_ += bf_lo(h[j].y); s3_ += bf_hi(h[j].y);
                s4_ += bf_lo(h[j].z); s5_ += bf_hi(h[j].z);
                s6_ += bf_lo(h[j].w); s7_ += bf_hi(h[j].w);
            }
        }
        for (; e < e1; ++e) {
            const uint4 h = *(const uint4*)(H + (size_t)csr[e] * 128 + l * 8);
            s0_ += bf_lo(h.x); s1_ += bf_hi(h.x);
            s2_ += bf_lo(h.y); s3_ += bf_hi(h.y);
            s4_ += bf_lo(h.z); s5_ += bf_hi(h.z);
            s6_ += bf_lo(h.w); s7_ += bf_hi(h.w);
        }
    }

    const float o0 = fmaxf(s0_ * dn + bA.x, 0.0f);
    const float o1 = fmaxf(s1_ * dn + bA.y, 0.0f);
    const float o2 = fmaxf(s2_ * dn + bA.z, 0.0f);
    const float o3 = fmaxf(s3_ * dn + bA.w, 0.0f);
    const float o4 = fmaxf(s4_ * dn + bB.x, 0.0f);
    const float o5 = fmaxf(s5_ * dn + bB.y, 0.0f);
    const float o6 = fmaxf(s6_ * dn + bB.z, 0.0f);
    const float o7 = fmaxf(s7_ * dn + bB.w, 0.0f);

    __shared__ float x3[16][128];
    __shared__ int bv[16];
    if (valid) {
        float4 va, vb;
        va.x = o0; va.y = o1; va.z = o2; va.w = o3;
        vb.x = o4; vb.y = o5; vb.z = o6; vb.w = o7;
        *(float4*)&x3[g][l * 8]     = va;
        *(float4*)&x3[g][l * 8 + 4] = vb;
        if (l == 0) bv[g] = batch[node];
    } else if (l == 0) {
        bv[g] = -1;
    }
    __syncthreads();
    const int t = threadIdx.x;
    if (t < 128) {
        int cur = bv[0];
        float run = 0.0f;
        for (int r = 0; r < 16; ++r) {
            const int b = bv[r];
            if (b < 0) break;
            if (b != cur) {
                if (run != 0.0f) atomicAdd(&pooled[(size_t)cur * 128 + t], run);
                cur = b; run = 0.0f;
            }
            run += x3[r][t];
        }
        if (cur >= 0 && run != 0.0f) atomicAdd(&pooled[(size_t)cur * 128 + t], run);
    }
}

// ---------------------------------------------------------------------------
// Pool finalize: counts via binary search on sorted batch, divide, 128x10.
// ---------------------------------------------------------------------------
__global__ __launch_bounds__(128) void pool_finalize(const float* __restrict__ pooled,
                                                     const int* __restrict__ batch,
                                                     const float* __restrict__ lw,
                                                     const float* __restrict__ lb,
                                                     float* __restrict__ out, int n) {
    const int g = blockIdx.x;
    const int t = threadIdx.x;
    int lo = 0, hi = n;
    while (lo < hi) { int mid = (lo + hi) >> 1; if (batch[mid] < g) lo = mid + 1; else hi = mid; }
    const int s = lo;
    hi = n;
    while (lo < hi) { int mid = (lo + hi) >> 1; if (batch[mid] < g + 1) lo = mid + 1; else hi = mid; }
    const float c = fmaxf((float)(lo - s), 1.0f);

    __shared__ float pl[128];
    pl[t] = pooled[(size_t)g * 128 + t] / c;
    __syncthreads();
    if (t < 10) {
        float acc = lb[t];
#pragma unroll 16
        for (int d = 0; d < 128; ++d) acc += pl[d] * lw[d * 10 + t];
        out[g * 10 + t] = acc;
    }
}

// ---------------------------------------------------------------------------
extern "C" void kernel_launch(void* const* d_in, const int* in_sizes, int n_in,
                              void* d_out, int out_size, void* d_ws, size_t ws_size,
                              hipStream_t stream) {
    const int*   tokens = (const int*)d_in[0];
    const int*   eidx   = (const int*)d_in[1];
    const int*   batch  = (const int*)d_in[2];
    const float* emb    = (const float*)d_in[3];
    const float* w1     = (const float*)d_in[4];
    const float* b1     = (const float*)d_in[5];
    const float* w2     = (const float*)d_in[6];
    const float* b2     = (const float*)d_in[7];
    const float* lw     = (const float*)d_in[8];
    const float* lbv    = (const float*)d_in[9];

    const int N = in_sizes[0];
    const int E = in_sizes[1] / 2;
    const int G = out_size / 10;
    const int* src = eidx;
    const int* dst = eidx + E;
    const int NB = (N + 255) >> 8;
    const int GB = (N + 127) / 128;

    char* p = (char*)d_ws;
    auto alloc = [&](size_t bytes) { void* r = (void*)p; p += (bytes + 255) & ~(size_t)255; return r; };
    float*  dis    = (float*)alloc((size_t)N * 4);
    int*    rbeg   = (int*)  alloc((size_t)N * 4);
    int*    rend   = (int*)  alloc((size_t)N * 4);
    int*    bcur   = (int*)  alloc(256 * 4);
    float*  pooled = (float*)alloc((size_t)G * 128 * 4);
    uint*   bstage = (uint*) alloc((size_t)NB * CAP * 4);
    int*    csr    = (int*)  alloc((size_t)NB * CAP * 4);
    ushort* W1t    = (ushort*)alloc(16384 * 2);
    ushort* W2t    = (ushort*)alloc(16384 * 2);
    ushort* A      = (ushort*)alloc((size_t)N * 128 * 2);   // H (bf16)
    ushort* B      = (ushort*)alloc((size_t)N * 128 * 2);   // Hs2 (bf16)

    const int PZ4 = (G * 128) / 4;
    const int PZB = (PZ4 + 255) / 256;
    const int EB  = (E + EPB - 1) / EPB;

    // L0: bcur zero + weight convert
    init0<<<129, 256, 0, stream>>>(bcur, w1, w2, W1t, W2t);
    // L1: scatter (blocks 0..EB) || gemm1 unscaled (EB..EB+GB) — independent
    scatter_gemm1_fused<<<EB + GB, 256, 0, stream>>>(src, dst, bcur, bstage,
                                                     tokens, emb, W1t, A, E, NB, EB, N);
    // L2: csr_build | pooled zero
    csr_poolz<<<NB + PZB, 256, 0, stream>>>(bstage, bcur, dis, rbeg, rend, csr,
                                            (int4*)pooled, PZ4, N, NB);
    // L3: agg1 + gemm2 fused (wave-autonomous): Hs2 = (relu(agg(H)+b1) @ W2) * dis
    agg1_gemm2<<<(N + 15) / 16, 256, 0, stream>>>(A, dis, rbeg, rend, csr, b1, W2t, B, N);
    // L4: agg2 (pure sum) + pooled partials
    aggregate_pool<<<(N + 15) / 16, 256, 0, stream>>>(B, dis, rbeg, rend, csr, b2, batch, pooled, N);
    // L5: finalize
    pool_finalize<<<G, 128, 0, stream>>>(pooled, batch, lw, lbv, (float*)d_out, N);
}

// Round 17
// 132.559 us; speedup vs baseline: 1.2882x; 1.2882x over previous
//
#include <hip/hip_runtime.h>
#include <hip/hip_bf16.h>

// ---------------------------------------------------------------------------
// GCN classifier.  R4: bucketed counting-sort CSR.  R6: MFMA GEMM.
// R9: fixed buckets, agg unroll 8.  R10: pre-scale + pool fusion.
// R11/R13: scatter||gemm1; csr_build+poolzero.  R14: gemm2 fused into agg1
//      (16-row LDS tile, barrier, 2 col-tiles/wave, B-frags from W2t once).
// R12 (REVERTED): XCD col-slicing — sub-line gathers, undefined XCD mapping.
// R15 (REVERTED): degree-sort perm — scattered Hs2 writes (RMW) + perm load
//      on gather critical path.
// R16 (REVERTED): wave-autonomous phase 2 — 4x MFMA + 4x W2t B-operand
//      traffic per block dwarfed the removed straggler cost (47->86us).
// R17: exact R14 restore (empirical optimum; 132.8us, absmax 4.88e-4).
// ---------------------------------------------------------------------------

typedef unsigned int uint;
typedef unsigned short ushort;
typedef __attribute__((ext_vector_type(8))) short bf16x8;
typedef __attribute__((ext_vector_type(4))) float f32x4;

__device__ inline float bf_lo(uint u) { return __uint_as_float(u << 16); }
__device__ inline float bf_hi(uint u) { return __uint_as_float(u & 0xffff0000u); }
__device__ inline ushort f2bf(float f) {           // round-to-nearest-even
    uint u = __float_as_uint(f);
    return (ushort)((u + 0x7fffu + ((u >> 16) & 1u)) >> 16);
}
__device__ inline uint pack2bf(float a, float b) {
    return (uint)f2bf(a) | ((uint)f2bf(b) << 16);
}

#define EPB 2048   // edges per block in bucketing kernels
#define CAP 8192   // per-bucket staged-edge capacity (avg 4082, Poisson tail ~0)

// ---- 0) zero bcur (block 0) + convert both weights (blocks 1..128) --------
__global__ __launch_bounds__(256) void init0(int* __restrict__ bcur,
                                             const float* __restrict__ W1,
                                             const float* __restrict__ W2,
                                             ushort* __restrict__ W1t,
                                             ushort* __restrict__ W2t) {
    if (blockIdx.x == 0) {
        bcur[threadIdx.x] = 0;
    } else {
        int i = (blockIdx.x - 1) * 256 + threadIdx.x;    // 0..32767
        const float* Ws = (i < 16384) ? W1 : W2;
        ushort* Wd      = (i < 16384) ? W1t : W2t;
        int j = i & 16383;
        int nn = j >> 7, k = j & 127;
        Wd[j] = f2bf(Ws[k * 128 + nn]);
    }
}

// ---- scatter body (uses caller-provided LDS: 1284 ints + 2048 uints) ------
__device__ void scatter_body(int* lds,
                             const int* __restrict__ src,
                             const int* __restrict__ dst,
                             int* __restrict__ bcur,
                             uint* __restrict__ bstage,
                             int E, int NB, int bid) {
    int*  lh    = lds;            // 256
    int*  lbase = lds + 256;      // 257
    int*  gbase = lds + 513;      // 256
    int*  lcur  = lds + 769;      // 256
    int*  ls    = lds + 1025;     // 256
    uint* stage = (uint*)(lds + 1284);   // 2048
    const int t = threadIdx.x;
    const int base = bid * EPB;
    const int end  = min(E, base + EPB);
    const int tot  = end - base;

    lh[t] = 0;
    __syncthreads();

    uint pk[8]; int bk[8]; int cnt = 0;
    for (int i = base + t; i < end; i += 256) {
        int s = src[i];
        uint d = (uint)dst[i];
        bk[cnt] = (int)(d >> 8);
        pk[cnt] = (uint)s | ((d & 255u) << 24);
        atomicAdd(&lh[bk[cnt]], 1);
        ++cnt;
    }
    __syncthreads();

    if (t < NB && lh[t]) gbase[t] = t * CAP + atomicAdd(&bcur[t], lh[t]);
    {
        int v = lh[t];
        ls[t] = v;
        __syncthreads();
        for (int off = 1; off < 256; off <<= 1) {
            int x = (t >= off) ? ls[t - off] : 0;
            __syncthreads();
            ls[t] += x;
            __syncthreads();
        }
        lbase[t] = ls[t] - v;
        if (t == 255) lbase[256] = ls[255];
        lcur[t] = 0;
    }
    __syncthreads();

    for (int j = 0; j < cnt; ++j) {
        int p = lbase[bk[j]] + atomicAdd(&lcur[bk[j]], 1);
        stage[p] = pk[j];
    }
    __syncthreads();

    for (int i = t; i < tot; i += 256) {
        int lo = 0, hi = 256;
        while (lo + 1 < hi) {
            int mid = (lo + hi) >> 1;
            if (lbase[mid] <= i) lo = mid; else hi = mid;
        }
        bstage[gbase[lo] + (i - lbase[lo])] = stage[i];
    }
}

// ---- csr_build body (uses caller-provided 4KB of LDS) ---------------------
__device__ void csr_body(int* lds,
                         const uint* __restrict__ bstage,
                         const int* __restrict__ bcur,
                         float* __restrict__ dis,
                         int* __restrict__ rbeg,
                         int* __restrict__ rend,
                         int* __restrict__ csr,
                         int N, int b) {
    int* lh    = lds;
    int* ls    = lds + 256;
    int* lbase = lds + 512;
    int* lcur  = lds + 768;
    const int t = threadIdx.x;
    const int base  = b * CAP;
    const int cntb  = bcur[b];
    const int n0    = b << 8;
    const int nn    = min(256, N - n0);

    lh[t] = 0;
    __syncthreads();
    for (int i = t; i < cntb; i += 256)
        atomicAdd(&lh[bstage[base + i] >> 24], 1);
    __syncthreads();

    const int v = lh[t];
    ls[t] = v;
    __syncthreads();
    for (int off = 1; off < 256; off <<= 1) {
        int x = (t >= off) ? ls[t - off] : 0;
        __syncthreads();
        ls[t] += x;
        __syncthreads();
    }
    lbase[t] = ls[t] - v;
    lcur[t] = 0;
    if (t < nn) {
        dis[n0 + t]  = rsqrtf((float)v + 1.0f);
        rbeg[n0 + t] = base + lbase[t];
        rend[n0 + t] = base + lbase[t] + v;
    }
    __syncthreads();

    for (int i = t; i < cntb; i += 256) {
        uint e = bstage[base + i];
        int dl = (int)(e >> 24);
        int pos = base + lbase[dl] + atomicAdd(&lcur[dl], 1);
        csr[pos] = (int)(e & 0xFFFFFFu);
    }
}

// ---- MFMA GEMM body (uses caller-provided 32KB LDS) ------------------------
// Out_bf16[n,128] = (A[n,128] @ W[128,128]) * (SCALE ? dis[row] : 1)
template<bool GATHER, bool SCALE>
__device__ void gemm_body(ushort* wl,
                          const ushort* __restrict__ Xbf,
                          const int* __restrict__ tokens,
                          const float* __restrict__ emb,
                          const ushort* __restrict__ Wt,
                          const float* __restrict__ dis,
                          ushort* __restrict__ Out, int n, int bid) {
    const int tid = threadIdx.x;
    {
        const int row  = tid >> 1;
        const int half = tid & 1;
        const int base = row * 256 + half * 128;
#pragma unroll
        for (int i = 0; i < 8; ++i) {
            int off = base + i * 16;
            uint4 v = *(const uint4*)((const char*)Wt + off);
            int swz = off ^ ((row & 7) << 4);
            *(uint4*)((char*)wl + swz) = v;
        }
    }
    __syncthreads();

    const int w  = tid >> 6;
    const int l  = tid & 63;
    const int lr = l & 15;
    const int lg = l >> 4;
    const int rowBase = bid * 128 + w * 32;

    f32x4 acc[2][8];
#pragma unroll
    for (int s = 0; s < 2; ++s)
#pragma unroll
        for (int ct = 0; ct < 8; ++ct) acc[s][ct] = (f32x4){0.f, 0.f, 0.f, 0.f};

    bf16x8 afrag[2][4];
#pragma unroll
    for (int s = 0; s < 2; ++s) {
        const int row = rowBase + s * 16 + lr;
        if (row < n) {
            if (GATHER) {
                const int tok = tokens[row];
                if (tok != 0) {
                    const float* ep = emb + (size_t)tok * 128;
#pragma unroll
                    for (int kk = 0; kk < 4; ++kk) {
                        const float* q = ep + kk * 32 + lg * 8;
                        float4 lo = *(const float4*)q;
                        float4 hi = *(const float4*)(q + 4);
                        uint4 pk;
                        pk.x = pack2bf(lo.x, lo.y); pk.y = pack2bf(lo.z, lo.w);
                        pk.z = pack2bf(hi.x, hi.y); pk.w = pack2bf(hi.z, hi.w);
                        union { uint4 u; bf16x8 b; } c; c.u = pk;
                        afrag[s][kk] = c.b;
                    }
                } else {
#pragma unroll
                    for (int kk = 0; kk < 4; ++kk) afrag[s][kk] = (bf16x8){0,0,0,0,0,0,0,0};
                }
            } else {
                const ushort* xp = Xbf + (size_t)row * 128;
#pragma unroll
                for (int kk = 0; kk < 4; ++kk)
                    afrag[s][kk] = *(const bf16x8*)(xp + kk * 32 + lg * 8);
            }
        } else {
#pragma unroll
            for (int kk = 0; kk < 4; ++kk) afrag[s][kk] = (bf16x8){0,0,0,0,0,0,0,0};
        }
    }

#pragma unroll
    for (int ct = 0; ct < 8; ++ct) {
#pragma unroll
        for (int kk = 0; kk < 4; ++kk) {
            const int nrow = ct * 16 + lr;
            int off = nrow * 256 + kk * 64 + lg * 16;
            off ^= ((nrow & 7) << 4);
            bf16x8 b = *(const bf16x8*)((const char*)wl + off);
            acc[0][ct] = __builtin_amdgcn_mfma_f32_16x16x32_bf16(afrag[0][kk], b, acc[0][ct], 0, 0, 0);
            acc[1][ct] = __builtin_amdgcn_mfma_f32_16x16x32_bf16(afrag[1][kk], b, acc[1][ct], 0, 0, 0);
        }
    }

#pragma unroll
    for (int s = 0; s < 2; ++s) {
#pragma unroll
        for (int r = 0; r < 4; ++r) {
            const int row = rowBase + s * 16 + lg * 4 + r;
            if (row < n) {
                const float sc = SCALE ? dis[row] : 1.0f;
                ushort* op = Out + (size_t)row * 128 + lr;
#pragma unroll
                for (int ct = 0; ct < 8; ++ct)
                    op[ct * 16] = f2bf(acc[s][ct][r] * sc);
            }
        }
    }
}

// ---- L1: fused scatter (blocks 0..EB) | gemm1 (EB..EB+GB) ------------------
__global__ __launch_bounds__(256) void scatter_gemm1_fused(const int* __restrict__ src,
                                                           const int* __restrict__ dst,
                                                           int* __restrict__ bcur,
                                                           uint* __restrict__ bstage,
                                                           const int* __restrict__ tokens,
                                                           const float* __restrict__ emb,
                                                           const ushort* __restrict__ W1t,
                                                           ushort* __restrict__ H,
                                                           int E, int NB, int EB, int N) {
    __shared__ ushort wl[128 * 128];   // 32KB; scatter path aliases 13.3KB
    const int b = blockIdx.x;
    if (b < EB) {
        scatter_body((int*)wl, src, dst, bcur, bstage, E, NB, b);
    } else {
        gemm_body<true, false>(wl, nullptr, tokens, emb, W1t, nullptr, H, N, b - EB);
    }
}

// ---- L2: csr_build (blocks 0..NB) | pooled zero ----------------------------
__global__ __launch_bounds__(256) void csr_poolz(const uint* __restrict__ bstage,
                                                 const int* __restrict__ bcur,
                                                 float* __restrict__ dis,
                                                 int* __restrict__ rbeg,
                                                 int* __restrict__ rend,
                                                 int* __restrict__ csr,
                                                 int4* __restrict__ poolz, int pz4,
                                                 int N, int NB) {
    __shared__ int lds[1024];
    const int b = blockIdx.x;
    if (b < NB) {
        csr_body(lds, bstage, bcur, dis, rbeg, rend, csr, N, b);
    } else {
        int i = (b - NB) * 256 + threadIdx.x;
        if (i < pz4) poolz[i] = make_int4(0, 0, 0, 0);
    }
}

// ---------------------------------------------------------------------------
// L3: agg1 + gemm2 fused (R14 structure).
// Phase 1: per node (16 lanes, full 256B rows)
//   o = relu( dn*sum_e H[src]*dis[src] + H[node]*dn^2 + b1 )   [f32 -> bf16]
//   staged into 4KB LDS with (row&7)<<4 swizzle.  __syncthreads.
// Phase 2: Hs2[16 rows] = (X2_tile @ W2) * dis — 4 waves x 2 col-tiles x
//   4 k-chunk MFMAs; B-frags straight from global W2t (L1/L2-resident 32KB).
// ---------------------------------------------------------------------------
__global__ __launch_bounds__(256) void agg1_gemm2(const ushort* __restrict__ H,
                                                  const float* __restrict__ dis,
                                                  const int* __restrict__ rbeg,
                                                  const int* __restrict__ rend,
                                                  const int* __restrict__ csr,
                                                  const float* __restrict__ bias,
                                                  const ushort* __restrict__ W2t,
                                                  ushort* __restrict__ Hs2,
                                                  int n) {
    const int g = threadIdx.x >> 4;
    const int l = threadIdx.x & 15;
    const int node = blockIdx.x * 16 + g;
    const bool valid = node < n;

    float s0_=0.f,s1_=0.f,s2_=0.f,s3_=0.f,s4_=0.f,s5_=0.f,s6_=0.f,s7_=0.f;
    float dn = 0.f;
    const float4 bA = *(const float4*)&bias[l * 8];
    const float4 bB = *(const float4*)&bias[l * 8 + 4];
    float hx0=0.f,hx1=0.f,hx2=0.f,hx3=0.f,hx4=0.f,hx5=0.f,hx6=0.f,hx7=0.f;

    if (valid) {
        dn = dis[node];
        const uint4 hq = *(const uint4*)(H + (size_t)node * 128 + l * 8);
        hx0 = bf_lo(hq.x); hx1 = bf_hi(hq.x);
        hx2 = bf_lo(hq.y); hx3 = bf_hi(hq.y);
        hx4 = bf_lo(hq.z); hx5 = bf_hi(hq.z);
        hx6 = bf_lo(hq.w); hx7 = bf_hi(hq.w);

        const int e0 = rbeg[node];
        const int e1 = rend[node];
        int e = e0;
        for (; e + 8 <= e1; e += 8) {
            int a[8];
#pragma unroll
            for (int j = 0; j < 8; ++j) a[j] = csr[e + j];
            float w[8];
#pragma unroll
            for (int j = 0; j < 8; ++j) w[j] = dis[a[j]];
            uint4 h[8];
#pragma unroll
            for (int j = 0; j < 8; ++j) h[j] = *(const uint4*)(H + (size_t)a[j] * 128 + l * 8);
#pragma unroll
            for (int j = 0; j < 8; ++j) {
                s0_ += bf_lo(h[j].x) * w[j]; s1_ += bf_hi(h[j].x) * w[j];
                s2_ += bf_lo(h[j].y) * w[j]; s3_ += bf_hi(h[j].y) * w[j];
                s4_ += bf_lo(h[j].z) * w[j]; s5_ += bf_hi(h[j].z) * w[j];
                s6_ += bf_lo(h[j].w) * w[j]; s7_ += bf_hi(h[j].w) * w[j];
            }
        }
        for (; e + 4 <= e1; e += 4) {
            int a[4];
#pragma unroll
            for (int j = 0; j < 4; ++j) a[j] = csr[e + j];
            float w[4];
#pragma unroll
            for (int j = 0; j < 4; ++j) w[j] = dis[a[j]];
            uint4 h[4];
#pragma unroll
            for (int j = 0; j < 4; ++j) h[j] = *(const uint4*)(H + (size_t)a[j] * 128 + l * 8);
#pragma unroll
            for (int j = 0; j < 4; ++j) {
                s0_ += bf_lo(h[j].x) * w[j]; s1_ += bf_hi(h[j].x) * w[j];
                s2_ += bf_lo(h[j].y) * w[j]; s3_ += bf_hi(h[j].y) * w[j];
                s4_ += bf_lo(h[j].z) * w[j]; s5_ += bf_hi(h[j].z) * w[j];
                s6_ += bf_lo(h[j].w) * w[j]; s7_ += bf_hi(h[j].w) * w[j];
            }
        }
        for (; e < e1; ++e) {
            const int a = csr[e];
            const float w = dis[a];
            const uint4 h = *(const uint4*)(H + (size_t)a * 128 + l * 8);
            s0_ += bf_lo(h.x)*w; s1_ += bf_hi(h.x)*w;
            s2_ += bf_lo(h.y)*w; s3_ += bf_hi(h.y)*w;
            s4_ += bf_lo(h.z)*w; s5_ += bf_hi(h.z)*w;
            s6_ += bf_lo(h.w)*w; s7_ += bf_hi(h.w)*w;
        }
    }

    const float self = dn * dn;
    uint4 o;
    o.x = pack2bf(fmaxf(s0_ * dn + hx0 * self + bA.x, 0.0f),
                  fmaxf(s1_ * dn + hx1 * self + bA.y, 0.0f));
    o.y = pack2bf(fmaxf(s2_ * dn + hx2 * self + bA.z, 0.0f),
                  fmaxf(s3_ * dn + hx3 * self + bA.w, 0.0f));
    o.z = pack2bf(fmaxf(s4_ * dn + hx4 * self + bB.x, 0.0f),
                  fmaxf(s5_ * dn + hx5 * self + bB.y, 0.0f));
    o.w = pack2bf(fmaxf(s6_ * dn + hx6 * self + bB.z, 0.0f),
                  fmaxf(s7_ * dn + hx7 * self + bB.w, 0.0f));

    // stage X2 tile (16 rows x 128 cols bf16) in LDS, (row&7)<<4 swizzle
    __shared__ ushort x2[16 * 128];
    {
        int boff = (g << 8) + (l << 4);
        boff ^= (g & 7) << 4;
        *(uint4*)((char*)x2 + boff) = o;
    }
    __syncthreads();

    // ---- phase 2: 16x128 @ 128x128 MFMA, wave w covers col tiles 2w,2w+1
    const int w   = threadIdx.x >> 6;
    const int l64 = threadIdx.x & 63;
    const int lr  = l64 & 15;
    const int lg  = l64 >> 4;

    bf16x8 afr[4];
#pragma unroll
    for (int kk = 0; kk < 4; ++kk) {
        int roff = (lr << 8) + (kk << 6) + (lg << 4);
        roff ^= (lr & 7) << 4;
        afr[kk] = *(const bf16x8*)((const char*)x2 + roff);
    }

    f32x4 acc[2];
    acc[0] = (f32x4){0.f, 0.f, 0.f, 0.f};
    acc[1] = (f32x4){0.f, 0.f, 0.f, 0.f};
#pragma unroll
    for (int ci = 0; ci < 2; ++ci) {
        const int ct = (w << 1) | ci;
#pragma unroll
        for (int kk = 0; kk < 4; ++kk) {
            bf16x8 b = *(const bf16x8*)(W2t + (size_t)(ct * 16 + lr) * 128 + kk * 32 + lg * 8);
            acc[ci] = __builtin_amdgcn_mfma_f32_16x16x32_bf16(afr[kk], b, acc[ci], 0, 0, 0);
        }
    }

#pragma unroll
    for (int r = 0; r < 4; ++r) {
        const int row = blockIdx.x * 16 + lg * 4 + r;
        if (row < n) {
            const float sc = dis[row];
            ushort* op = Hs2 + (size_t)row * 128 + lr;
            op[(w * 2) * 16]     = f2bf(acc[0][r] * sc);
            op[(w * 2 + 1) * 16] = f2bf(acc[1][r] * sc);
        }
    }
}

// ---------------------------------------------------------------------------
// agg2 over pre-scaled Hs (natural node order), fused with mean-pool partials.
// ---------------------------------------------------------------------------
__global__ __launch_bounds__(256) void aggregate_pool(const ushort* __restrict__ H,
                                                      const float* __restrict__ dis,
                                                      const int* __restrict__ rbeg,
                                                      const int* __restrict__ rend,
                                                      const int* __restrict__ csr,
                                                      const float* __restrict__ bias,
                                                      const int* __restrict__ batch,
                                                      float* __restrict__ pooled,
                                                      int n) {
    const int g = threadIdx.x >> 4;
    const int l = threadIdx.x & 15;
    const int node = blockIdx.x * 16 + g;
    const bool valid = node < n;

    float s0_=0.f,s1_=0.f,s2_=0.f,s3_=0.f,s4_=0.f,s5_=0.f,s6_=0.f,s7_=0.f;
    float dn = 0.f;
    const float4 bA = *(const float4*)&bias[l * 8];
    const float4 bB = *(const float4*)&bias[l * 8 + 4];

    if (valid) {
        dn = dis[node];
        const uint4 hq = *(const uint4*)(H + (size_t)node * 128 + l * 8);
        s0_ = bf_lo(hq.x); s1_ = bf_hi(hq.x);
        s2_ = bf_lo(hq.y); s3_ = bf_hi(hq.y);
        s4_ = bf_lo(hq.z); s5_ = bf_hi(hq.z);
        s6_ = bf_lo(hq.w); s7_ = bf_hi(hq.w);

        const int e0 = rbeg[node];
        const int e1 = rend[node];
        int e = e0;
        for (; e + 8 <= e1; e += 8) {
            int a[8];
#pragma unroll
            for (int j = 0; j < 8; ++j) a[j] = csr[e + j];
            uint4 h[8];
#pragma unroll
            for (int j = 0; j < 8; ++j) h[j] = *(const uint4*)(H + (size_t)a[j] * 128 + l * 8);
#pragma unroll
            for (int j = 0; j < 8; ++j) {
                s0_ += bf_lo(h[j].x); s1_ += bf_hi(h[j].x);
                s2_ += bf_lo(h[j].y); s3_ += bf_hi(h[j].y);
                s4_ += bf_lo(h[j].z); s5_ += bf_hi(h[j].z);
                s6_ += bf_lo(h[j].w); s7_ += bf_hi(h[j].w);
            }
        }
        for (; e + 4 <= e1; e += 4) {
            int a[4];
#pragma unroll
            for (int j = 0; j < 4; ++j) a[j] = csr[e + j];
            uint4 h[4];
#pragma unroll
            for (int j = 0; j < 4; ++j) h[j] = *(const uint4*)(H + (size_t)a[j] * 128 + l * 8);
#pragma unroll
            for (int j = 0; j < 4; ++j) {
                s0_ += bf_lo(h[j].x); s1_ += bf_hi(h[j].x);
                s2_ += bf_lo(h[j].y); s3_ += bf_hi(h[j].y);
                s4_ += bf_lo(h[j].z); s5_ += bf_hi(h[j].z);
                s6_ += bf_lo(h[j].w); s7_ += bf_hi(h[j].w);
            }
        }
        for (; e < e1; ++e) {
            const uint4 h = *(const uint4*)(H + (size_t)csr[e] * 128 + l * 8);
            s0_ += bf_lo(h.x); s1_ += bf_hi(h.x);
            s2_ += bf_lo(h.y); s3_ += bf_hi(h.y);
            s4_ += bf_lo(h.z); s5_ += bf_hi(h.z);
            s6_ += bf_lo(h.w); s7_ += bf_hi(h.w);
        }
    }

    const float o0 = fmaxf(s0_ * dn + bA.x, 0.0f);
    const float o1 = fmaxf(s1_ * dn + bA.y, 0.0f);
    const float o2 = fmaxf(s2_ * dn + bA.z, 0.0f);
    const float o3 = fmaxf(s3_ * dn + bA.w, 0.0f);
    const float o4 = fmaxf(s4_ * dn + bB.x, 0.0f);
    const float o5 = fmaxf(s5_ * dn + bB.y, 0.0f);
    const float o6 = fmaxf(s6_ * dn + bB.z, 0.0f);
    const float o7 = fmaxf(s7_ * dn + bB.w, 0.0f);

    __shared__ float x3[16][128];
    __shared__ int bv[16];
    if (valid) {
        float4 va, vb;
        va.x = o0; va.y = o1; va.z = o2; va.w = o3;
        vb.x = o4; vb.y = o5; vb.z = o6; vb.w = o7;
        *(float4*)&x3[g][l * 8]     = va;
        *(float4*)&x3[g][l * 8 + 4] = vb;
        if (l == 0) bv[g] = batch[node];
    } else if (l == 0) {
        bv[g] = -1;
    }
    __syncthreads();
    const int t = threadIdx.x;
    if (t < 128) {
        int cur = bv[0];
        float run = 0.0f;
        for (int r = 0; r < 16; ++r) {
            const int b = bv[r];
            if (b < 0) break;
            if (b != cur) {
                if (run != 0.0f) atomicAdd(&pooled[(size_t)cur * 128 + t], run);
                cur = b; run = 0.0f;
            }
            run += x3[r][t];
        }
        if (cur >= 0 && run != 0.0f) atomicAdd(&pooled[(size_t)cur * 128 + t], run);
    }
}

// ---------------------------------------------------------------------------
// Pool finalize: counts via binary search on sorted batch, divide, 128x10.
// ---------------------------------------------------------------------------
__global__ __launch_bounds__(128) void pool_finalize(const float* __restrict__ pooled,
                                                     const int* __restrict__ batch,
                                                     const float* __restrict__ lw,
                                                     const float* __restrict__ lb,
                                                     float* __restrict__ out, int n) {
    const int g = blockIdx.x;
    const int t = threadIdx.x;
    int lo = 0, hi = n;
    while (lo < hi) { int mid = (lo + hi) >> 1; if (batch[mid] < g) lo = mid + 1; else hi = mid; }
    const int s = lo;
    hi = n;
    while (lo < hi) { int mid = (lo + hi) >> 1; if (batch[mid] < g + 1) lo = mid + 1; else hi = mid; }
    const float c = fmaxf((float)(lo - s), 1.0f);

    __shared__ float pl[128];
    pl[t] = pooled[(size_t)g * 128 + t] / c;
    __syncthreads();
    if (t < 10) {
        float acc = lb[t];
#pragma unroll 16
        for (int d = 0; d < 128; ++d) acc += pl[d] * lw[d * 10 + t];
        out[g * 10 + t] = acc;
    }
}

// ---------------------------------------------------------------------------
extern "C" void kernel_launch(void* const* d_in, const int* in_sizes, int n_in,
                              void* d_out, int out_size, void* d_ws, size_t ws_size,
                              hipStream_t stream) {
    const int*   tokens = (const int*)d_in[0];
    const int*   eidx   = (const int*)d_in[1];
    const int*   batch  = (const int*)d_in[2];
    const float* emb    = (const float*)d_in[3];
    const float* w1     = (const float*)d_in[4];
    const float* b1     = (const float*)d_in[5];
    const float* w2     = (const float*)d_in[6];
    const float* b2     = (const float*)d_in[7];
    const float* lw     = (const float*)d_in[8];
    const float* lbv    = (const float*)d_in[9];

    const int N = in_sizes[0];
    const int E = in_sizes[1] / 2;
    const int G = out_size / 10;
    const int* src = eidx;
    const int* dst = eidx + E;
    const int NB = (N + 255) >> 8;
    const int GB = (N + 127) / 128;

    char* p = (char*)d_ws;
    auto alloc = [&](size_t bytes) { void* r = (void*)p; p += (bytes + 255) & ~(size_t)255; return r; };
    float*  dis    = (float*)alloc((size_t)N * 4);
    int*    rbeg   = (int*)  alloc((size_t)N * 4);
    int*    rend   = (int*)  alloc((size_t)N * 4);
    int*    bcur   = (int*)  alloc(256 * 4);
    float*  pooled = (float*)alloc((size_t)G * 128 * 4);
    uint*   bstage = (uint*) alloc((size_t)NB * CAP * 4);
    int*    csr    = (int*)  alloc((size_t)NB * CAP * 4);
    ushort* W1t    = (ushort*)alloc(16384 * 2);
    ushort* W2t    = (ushort*)alloc(16384 * 2);
    ushort* A      = (ushort*)alloc((size_t)N * 128 * 2);   // H (bf16)
    ushort* B      = (ushort*)alloc((size_t)N * 128 * 2);   // Hs2 (bf16)

    const int PZ4 = (G * 128) / 4;
    const int PZB = (PZ4 + 255) / 256;
    const int EB  = (E + EPB - 1) / EPB;

    // L0: bcur zero + weight convert
    init0<<<129, 256, 0, stream>>>(bcur, w1, w2, W1t, W2t);
    // L1: scatter (blocks 0..EB) || gemm1 unscaled (EB..EB+GB) — independent
    scatter_gemm1_fused<<<EB + GB, 256, 0, stream>>>(src, dst, bcur, bstage,
                                                     tokens, emb, W1t, A, E, NB, EB, N);
    // L2: csr_build | pooled zero
    csr_poolz<<<NB + PZB, 256, 0, stream>>>(bstage, bcur, dis, rbeg, rend, csr,
                                            (int4*)pooled, PZ4, N, NB);
    // L3: agg1 + gemm2 fused: Hs2 = (relu(agg(H)+b1) @ W2) * dis
    agg1_gemm2<<<(N + 15) / 16, 256, 0, stream>>>(A, dis, rbeg, rend, csr, b1, W2t, B, N);
    // L4: agg2 (pure sum) + pooled partials
    aggregate_pool<<<(N + 15) / 16, 256, 0, stream>>>(B, dis, rbeg, rend, csr, b2, batch, pooled, N);
    // L5: finalize
    pool_finalize<<<G, 128, 0, stream>>>(pooled, batch, lw, lbv, (float*)d_out, N);
}